// Round 1
// 961.595 us; speedup vs baseline: 1.1865x; 1.1865x over previous
//
#include <hip/hip_runtime.h>

// Fused 1->288ch 3x3 VALID conv + bias(full tensor) + ReLU, fp32.
// B=16, H=W=224, HOUT=WOUT=222, COUT=288.
// v2: LDS-staged x (2x float4 global loads/thread/batch instead of 36
// strided scalar loads), XOR-swizzled LDS layout (conflict-free reads),
// prefetch split (issue loads for b+1 before compute of b).
// Stores/bias layout unchanged: aligned float4, bias held in regs across batches.

constexpr int Bn    = 16;
constexpr int COUT  = 288;
constexpr int Hin   = 224;
constexpr int Win   = 224;
constexpr int HOUT  = 222;
constexpr int WOUT  = 222;
constexpr int PLANE = HOUT * WOUT;   // 49284, divisible by 4
constexpr int NF4   = PLANE / 4;     // 12321 float4 groups per plane
constexpr int XPLANE = Hin * Win;    // 50176

constexpr int POS_PER_BLOCK = 1024;  // 256 threads * 4 flat positions
constexpr int XROWS  = 8;            // x rows staged per block (strip spans <=6 out rows +2)
constexpr int LDSW   = XROWS * Win;  // 1792 words = 7168 B
constexpr int NCHUNK = LDSW / 4;     // 448 float4 chunks
constexpr int CPR    = Win / 4;      // 56 chunks per x row

// Swizzle: physical[q] = logical[q ^ ((q>>5)&3)].  Bits>=5 are unchanged by
// the XOR, so reader and writer agree on g; permutation is intra-16B-chunk,
// keeping ds_write_b128 aligned. Spreads the 4-word lane stride of the
// compute reads across all 32 banks (2 lanes/bank = free).
__device__ __forceinline__ float4 swz_permute(float4 v, int g) {
    const bool s1 = (g & 1) != 0;
    const bool s2 = (g & 2) != 0;
    float ax = s1 ? v.y : v.x, ay = s1 ? v.x : v.y;
    float az = s1 ? v.w : v.z, aw = s1 ? v.z : v.w;
    float4 d;
    d.x = s2 ? az : ax; d.y = s2 ? aw : ay;
    d.z = s2 ? ax : az; d.w = s2 ? ay : aw;
    return d;
}

__global__ __launch_bounds__(256) void conv_bias_relu(
    const float* __restrict__ x,     // (16,1,224,224)
    const float* __restrict__ w,     // (288,1,3,3)
    const float* __restrict__ bias,  // (1,288,222,222)
    float* __restrict__ out)         // (16,288,222,222)
{
    __shared__ __align__(16) float lds[LDSW];

    const int tid = threadIdx.x;
    const int bx  = blockIdx.x;
    const int co0 = blockIdx.y * 4;

    const int  f4r    = bx * 256 + tid;
    const bool active = f4r < NF4;
    const int  f4     = active ? f4r : (NF4 - 1);  // clamp: keep addrs valid
    const int  f      = f4 * 4;

    const int f0  = bx * POS_PER_BLOCK;
    const int ho0 = f0 / WOUT;                     // first out row of block

    // 3x3 weights for this block's 4 channels (block-uniform)
    float wv[4][9];
    #pragma unroll
    for (int c = 0; c < 4; ++c)
        #pragma unroll
        for (int k = 0; k < 9; ++k)
            wv[c][k] = w[(co0 + c) * 9 + k];

    // bias: one float4 per channel, read ONCE, reused for all 16 batches
    float4 bv[4];
    #pragma unroll
    for (int c = 0; c < 4; ++c)
        bv[c] = *reinterpret_cast<const float4*>(bias + (size_t)(co0 + c) * PLANE + f);

    // Swizzled LDS read addresses for the 4 positions' 3x3 windows
    // (batch-invariant; held in VGPRs)
    int ra[36];
    #pragma unroll
    for (int j = 0; j < 4; ++j) {
        const int fj = f + j;
        const int ho = fj / WOUT;                  // magic-mul
        const int wo = fj - ho * WOUT;
        const int base = (ho - ho0) * Win + wo;
        #pragma unroll
        for (int kh = 0; kh < 3; ++kh)
            #pragma unroll
            for (int kw = 0; kw < 3; ++kw) {
                const int wd = base + kh * Win + kw;
                ra[j * 9 + kh * 3 + kw] = wd ^ ((wd >> 5) & 3);
            }
    }

    // Staging geometry: thread handles chunks tid and tid+256 of 448
    const int  ch0  = tid;
    const int  ch1  = tid + 256;
    const bool has2 = ch1 < NCHUNK;

    const int r0    = ch0 / CPR;
    const int c0w   = (ch0 - r0 * CPR) * 4;
    const int srow0 = min(ho0 + r0, Hin - 1);      // clamp dup rows, unused
    const int soff0 = srow0 * Win + c0w;
    const int g0    = (ch0 >> 3) & 3;

    const int r1    = ch1 / CPR;
    const int c1w   = (ch1 - r1 * CPR) * 4;
    const int srow1 = min(ho0 + r1, Hin - 1);
    const int soff1 = srow1 * Win + c1w;
    const int g1    = (ch1 >> 3) & 3;

    // prefetch batch 0 into registers
    float4 p0, p1;
    p0 = *reinterpret_cast<const float4*>(x + soff0);
    if (has2) p1 = *reinterpret_cast<const float4*>(x + soff1);

    for (int b = 0; b < Bn; ++b) {
        __syncthreads();                           // prev compute done reading LDS
        reinterpret_cast<float4*>(lds)[ch0] = swz_permute(p0, g0);
        if (has2) reinterpret_cast<float4*>(lds)[ch1] = swz_permute(p1, g1);
        __syncthreads();                           // strip visible to all

        // issue next batch's loads now; latency hides under compute below
        if (b + 1 < Bn) {
            const float* xb = x + (b + 1) * XPLANE;
            p0 = *reinterpret_cast<const float4*>(xb + soff0);
            if (has2) p1 = *reinterpret_cast<const float4*>(xb + soff1);
        }

        float acc[4][4];
        #pragma unroll
        for (int c = 0; c < 4; ++c) {
            acc[c][0] = bv[c].x; acc[c][1] = bv[c].y;
            acc[c][2] = bv[c].z; acc[c][3] = bv[c].w;
        }

        #pragma unroll
        for (int j = 0; j < 4; ++j) {
            float xv[9];
            #pragma unroll
            for (int k = 0; k < 9; ++k)
                xv[k] = lds[ra[j * 9 + k]];
            #pragma unroll
            for (int c = 0; c < 4; ++c)
                #pragma unroll
                for (int k = 0; k < 9; ++k)
                    acc[c][j] = fmaf(wv[c][k], xv[k], acc[c][j]);
        }

        if (active) {
            #pragma unroll
            for (int c = 0; c < 4; ++c) {
                float4 o;
                o.x = fmaxf(acc[c][0], 0.f);
                o.y = fmaxf(acc[c][1], 0.f);
                o.z = fmaxf(acc[c][2], 0.f);
                o.w = fmaxf(acc[c][3], 0.f);
                *reinterpret_cast<float4*>(
                    out + (size_t)(b * COUT + co0 + c) * PLANE + f) = o;
            }
        }
    }
}

extern "C" void kernel_launch(void* const* d_in, const int* in_sizes, int n_in,
                              void* d_out, int out_size, void* d_ws, size_t ws_size,
                              hipStream_t stream) {
    const float* x    = (const float*)d_in[0];  // 16*1*224*224
    const float* w    = (const float*)d_in[1];  // 288*1*3*3
    const float* bias = (const float*)d_in[2];  // 1*288*222*222
    float* out        = (float*)d_out;          // 16*288*222*222

    dim3 block(256);
    dim3 grid((NF4 + 255) / 256, COUT / 4);     // 49 x 72
    conv_bias_relu<<<grid, block, 0, stream>>>(x, w, bias, out);
}